// Round 11
// baseline (468.301 us; speedup 1.0000x reference)
//
#include <hip/hip_runtime.h>

#define NB 16
#define NA 256
#define NNODES 4096
#define FEATD 64
#define HID 256
#define TEMBD 32
#define NUMT 100
#define NE 131072
#define NL 4
#define NCHUNK (NE / 16)   // 8192 16-edge chunks

typedef __attribute__((ext_vector_type(8))) short short8;
typedef __attribute__((ext_vector_type(4))) float f32x4;
typedef __attribute__((ext_vector_type(2))) float f32x2;

// fast silu: v * rcp(1 + exp2(-log2e * v))
__device__ __forceinline__ float silu_f(float v) {
    float s = __builtin_amdgcn_rcpf(1.f + __builtin_amdgcn_exp2f(-1.44269504f * v));
    return v * s;
}

__device__ __forceinline__ short f2bf(float f) {          // RNE
    union { float f; unsigned u; } v; v.f = f;
    unsigned r = (v.u + 0x7fffu + ((v.u >> 16) & 1u)) >> 16;
    return (short)r;
}
__device__ __forceinline__ short f2bf_t(float f) {        // truncate (intermediates)
    union { float f; unsigned u; } v; v.f = f;
    return (short)(v.u >> 16);
}
__device__ __forceinline__ float bf2f(short s) {
    union { float f; unsigned u; } v; v.u = ((unsigned)(unsigned short)s) << 16;
    return v.f;
}

__device__ __forceinline__ float block_sum(float v, float* red, int a) {
    red[a] = v; __syncthreads();
    for (int s = 128; s > 0; s >>= 1) {
        if (a < s) red[a] += red[a + s];
        __syncthreads();
    }
    float r = red[0]; __syncthreads();
    return r;
}

// ---------------------------------------------------------------- prep (+deg zero, +out zero, +x_cur init)
__global__ __launch_bounds__(256) void prep_kernel(
    const float* __restrict__ x0, const float* __restrict__ noise,
    const int* __restrict__ t,
    float* __restrict__ noise_c, float* __restrict__ xt, float* __restrict__ temb,
    int* __restrict__ deg, float* __restrict__ out, float* __restrict__ x_cur)
{
    __shared__ float red[256];
    __shared__ float sab_s[2];
    int b = blockIdx.x, a = threadIdx.x;
    int base = (b * NA + a) * 3;

    deg[b * 256 + a] = 0;
    if (b == 0 && a == 0) out[0] = 0.f;

    float nx = noise[base + 0], ny = noise[base + 1], nz = noise[base + 2];
    float mnx = block_sum(nx, red, a) * (1.f / NA);
    float mny = block_sum(ny, red, a) * (1.f / NA);
    float mnz = block_sum(nz, red, a) * (1.f / NA);
    nx -= mnx; ny -= mny; nz -= mnz;
    noise_c[base + 0] = nx; noise_c[base + 1] = ny; noise_c[base + 2] = nz;

    if (a == 0) {
        int tt = t[b];
        float p = 1.f;
        for (int i = 0; i < NUMT; i++) {
            float beta = 1e-4f + (0.02f - 1e-4f) * (float)i / (float)(NUMT - 1);
            if (i <= tt) p *= (1.f - beta);
        }
        sab_s[0] = sqrtf(p);
        sab_s[1] = sqrtf(1.f - p);
    }
    __syncthreads();
    float sab = sab_s[0], s1ab = sab_s[1];

    float xx = sab * x0[base + 0] + s1ab * nx;
    float xy = sab * x0[base + 1] + s1ab * ny;
    float xz = sab * x0[base + 2] + s1ab * nz;
    float mx = block_sum(xx, red, a) * (1.f / NA);
    float my = block_sum(xy, red, a) * (1.f / NA);
    float mz = block_sum(xz, red, a) * (1.f / NA);
    float vx = xx - mx, vy = xy - my, vz = xz - mz;
    xt[base + 0] = vx; xt[base + 1] = vy; xt[base + 2] = vz;
    x_cur[base + 0] = vx; x_cur[base + 1] = vy; x_cur[base + 2] = vz;

    if (a < TEMBD / 2) {
        float fr = expf(-logf(10000.f) * (float)a / (float)(TEMBD / 2 - 1));
        float ang = (float)t[b] * fr;
        temb[b * TEMBD + a] = sinf(ang);
        temb[b * TEMBD + TEMBD / 2 + a] = cosf(ang);
    }
}

// ---------------------------------------------------------------- CSR build
__global__ __launch_bounds__(256) void csr_hist(const int* __restrict__ row, int* __restrict__ deg)
{
    int i = blockIdx.x * 256 + threadIdx.x;
    if (i < NE) atomicAdd(&deg[row[i]], 1);
}

// scan + flag fused: cursor[r] = exclusive start offset; flag[r] = row has an
// interior run in some 16-edge chunk (direct m_i/x_agg store exists).
__global__ __launch_bounds__(256) void csr_scan(
    const int* __restrict__ deg, int* __restrict__ cursor, int* __restrict__ flag)
{
    __shared__ int s[256];
    int t = threadIdx.x;
    int base = t * 16;
    int loc[16], dg[16];
    int sum = 0;
    for (int i = 0; i < 16; i++) { dg[i] = deg[base + i]; loc[i] = sum; sum += dg[i]; }
    s[t] = sum; __syncthreads();
    for (int off = 1; off < 256; off <<= 1) {
        int v = (t >= off) ? s[t - off] : 0;
        __syncthreads();
        s[t] += v;
        __syncthreads();
    }
    int excl = (t == 0) ? 0 : s[t - 1];
    for (int i = 0; i < 16; i++) {
        int start = excl + loc[i];
        cursor[base + i] = start;
        int end = start + dg[i];
        int fl = 0;
        if (end > start) {
            int cs = start >> 4, ce = (end - 1) >> 4;
            for (int ch = cs; ch <= ce; ch++) {
                int rs = start > ch * 16 ? start : ch * 16;
                int re = end < ch * 16 + 16 ? end : ch * 16 + 16;
                if (rs > ch * 16 && re < ch * 16 + 16) fl = 1;
            }
        }
        flag[base + i] = fl;
    }
}

__global__ __launch_bounds__(256) void csr_scatter(
    const int* __restrict__ row, const int* __restrict__ col,
    int* __restrict__ cursor, int* __restrict__ prow, int* __restrict__ pcol)
{
    int i = blockIdx.x * 256 + threadIdx.x;
    if (i < NE) {
        int r = row[i];
        int p = atomicAdd(&cursor[r], 1);
        prow[p] = r;
        pcol[p] = col[i];
    }
}

// ---------------------------------------------------------------- weight convert (bf16 + fp8, one kernel)
// bf16 layout per weight: [kt][n(N)][kk(32)]
#define WOFF_EMB 0
#define WOFF_L(l) (24576 + (l) * 458752)
#define WOFF_AB 0
#define WOFF_E2 131072
#define WOFF_C1 196608
#define WOFF_N1 262144
#define WOFF_N2 393216
#define W_TOTAL (24576 + 4 * 458752)
#define WF8_TOTAL (4 * 2 * 65536)

__global__ __launch_bounds__(256) void convert_weights(
    const float* __restrict__ W_emb, const float* __restrict__ eW1,
    const float* __restrict__ eW2, const float* __restrict__ cW1,
    const float* __restrict__ nW1, const float* __restrict__ nW2,
    short* __restrict__ wb, char* __restrict__ wf8)
{
    int idx = blockIdx.x * 256 + threadIdx.x;
    if (idx >= W_TOTAL) {
        // fp8 e4m3 (x16 scaled) edge weights: [l][mat(E2,C1)][kt][n(256)][kk(32)]
        int i8 = idx - W_TOTAL;
        if (i8 >= WF8_TOTAL) return;
        int l = i8 >> 17;
        int o = i8 & 131071;
        int mat = o >> 16;
        int o2 = o & 65535;
        int k = o2 >> 8, n = o2 & 255;
        const float* src = (mat == 0 ? eW2 : cW1) + (size_t)l * 65536 + (size_t)k * 256 + n;
        float v = (*src) * 16.f;
        int p = __builtin_amdgcn_cvt_pk_fp8_f32(v, v, 0, false);
        wf8[(size_t)l * 131072 + mat * 65536 + (k >> 5) * 8192 + n * 32 + (k & 31)] = (char)(p & 0xff);
        return;
    }
    if (idx < 24576) {
        int k = idx >> 8, n = idx & 255;
        wb[WOFF_EMB + ((k >> 5) << 13) + (n << 5) + (k & 31)] = f2bf(W_emb[idx]);
        return;
    }
    int r = idx - 24576;
    int l = r / 458752;
    int o = r - l * 458752;
    if (o < 131072) {
        int k = o >> 9, n = o & 511;
        const float* src = eW1 + (size_t)l * 513 * 256 +
            (n < 256 ? (size_t)k * 256 + n : (size_t)(256 + k) * 256 + (n - 256));
        wb[WOFF_L(l) + WOFF_AB + ((k >> 5) * 16384) + (n << 5) + (k & 31)] = f2bf(*src);
        return;
    }
    const float* src; int dst; int o2;
    if (o < 196608)      { o2 = o - 131072; src = eW2 + (size_t)l * 65536 + o2;  dst = WOFF_L(l) + WOFF_E2; }
    else if (o < 262144) { o2 = o - 196608; src = cW1 + (size_t)l * 65536 + o2;  dst = WOFF_L(l) + WOFF_C1; }
    else if (o < 393216) { o2 = o - 262144; src = nW1 + (size_t)l * 131072 + o2; dst = WOFF_L(l) + WOFF_N1; }
    else                 { o2 = o - 393216; src = nW2 + (size_t)l * 65536 + o2;  dst = WOFF_L(l) + WOFF_N2; }
    int k = o2 >> 8, n = o2 & 255;
    wb[dst + ((k >> 5) << 13) + (n << 5) + (k & 31)] = f2bf(*src);
}

// ---------------------------------------------------------------- emb GEMM + layer0 P12 fused
// 8 nodes/block, 512 threads, grid 512 -> 2 blocks/CU for barrier overlap.
// A rows 8..15 duplicate row (lr&7); stores gated on q<2.
__global__ __launch_bounds__(512, 4) void emb_p12_fused(
    const float* __restrict__ h, const float* __restrict__ temb,
    const short* __restrict__ wtEmb,
    const float* __restrict__ b_emb, const short* __restrict__ wtAB,
    const float* __restrict__ eb1_0,
    short* __restrict__ hh, short* __restrict__ P12)
{
    __shared__ short h2s[8 * 264];
    int tid = threadIdx.x;
    int wv = tid >> 6, l = tid & 63;
    int lr = l & 15, q = l >> 4;
    int alr = lr & 7;
    int r0 = blockIdx.x * 8;

    // ---- stage A: hh = [h|temb] @ W_emb + b (K=96, 32 cols/wave)
    f32x4 acc[2];
    #pragma unroll
    for (int i = 0; i < 2; i++) acc[i] = (f32x4){0.f, 0.f, 0.f, 0.f};
    int n = r0 + alr;
    #pragma unroll
    for (int kt = 0; kt < 3; kt++) {
        int kk = kt * 32 + q * 8;
        const float* src = (kk < 64) ? &h[(size_t)n * 64 + kk]
                                     : &temb[(n >> 8) * 32 + kk - 64];
        short8 fa;
        #pragma unroll
        for (int k2 = 0; k2 < 8; k2++) fa[k2] = f2bf(src[k2]);
        #pragma unroll
        for (int nt = 0; nt < 2; nt++) {
            short8 fb = *(const short8*)&wtEmb[kt * 8192 + (wv * 32 + nt * 16 + lr) * 32 + q * 8];
            acc[nt] = __builtin_amdgcn_mfma_f32_16x16x32_bf16(fa, fb, acc[nt], 0, 0, 0);
        }
    }
    if (q < 2) {
        #pragma unroll
        for (int nt = 0; nt < 2; nt++) {
            int col = wv * 32 + nt * 16 + lr;
            float bv = b_emb[col];
            #pragma unroll
            for (int rg = 0; rg < 4; rg++) {
                int rrow = q * 4 + rg;
                short b = f2bf(acc[nt][rg] + bv);
                hh[(size_t)(r0 + rrow) * 256 + col] = b;
                h2s[rrow * 264 + col] = b;
            }
        }
    }
    __syncthreads();

    // ---- stage B: P12 = hh @ AB (N=512, 64 cols/wave), +eb1_0 on P1 half
    f32x4 acc3[4];
    #pragma unroll
    for (int i = 0; i < 4; i++) acc3[i] = (f32x4){0.f, 0.f, 0.f, 0.f};
    #pragma unroll 2
    for (int kt = 0; kt < 8; kt++) {
        short8 fa = *(const short8*)&h2s[alr * 264 + kt * 32 + q * 8];
        #pragma unroll
        for (int nt = 0; nt < 4; nt++) {
            short8 fb = *(const short8*)&wtAB[kt * 16384 + (wv * 64 + nt * 16 + lr) * 32 + q * 8];
            acc3[nt] = __builtin_amdgcn_mfma_f32_16x16x32_bf16(fa, fb, acc3[nt], 0, 0, 0);
        }
    }
    if (q < 2) {
        #pragma unroll
        for (int nt = 0; nt < 4; nt++) {
            int col = wv * 64 + nt * 16 + lr;
            float bv = (col < 256) ? eb1_0[col] : 0.f;
            #pragma unroll
            for (int rg = 0; rg < 4; rg++)
                P12[(size_t)(r0 + q * 4 + rg) * 512 + col] = f2bf(acc3[nt][rg] + bv);
        }
    }
}

// ---------------------------------------------------------------- node MLP + next P12
// 8 nodes/block, 512 threads, grid 512 -> 2 blocks/CU.
__global__ __launch_bounds__(512, 4) void node_p12_fused(
    const short* __restrict__ hc, const float* __restrict__ m_i,
    const int* __restrict__ cursor, const int* __restrict__ flag,
    const int* __restrict__ tag0, const int* __restrict__ tag1,
    const float* __restrict__ msl0, const float* __restrict__ msl1,
    const float* __restrict__ xsl0, const float* __restrict__ xsl1,
    const float* __restrict__ x_agg, float* __restrict__ x_cur,
    const short* __restrict__ wtN1, const float* __restrict__ nb1,
    const short* __restrict__ wtN2, const float* __restrict__ nb2,
    const short* __restrict__ wtAB, const float* __restrict__ eb1n,
    short* __restrict__ hn, short* __restrict__ P12)
{
    __shared__ short m_is[8 * 264];
    __shared__ short t1s[8 * 264];
    __shared__ short h2s[8 * 264];
    int tid = threadIdx.x;
    int wv = tid >> 6, l = tid & 63;
    int lr = l & 15, q = l >> 4;
    int alr = lr & 7;
    int r0 = blockIdx.x * 8;

    // ---- stage 0: m_i slot-merge -> LDS bf16 (4 cols/thread); x merge (tid<8)
    {
        int rr = tid >> 6;              // 0..7
        int cc = (tid & 63) * 4;
        int r = r0 + rr;
        float v[4] = {0.f, 0.f, 0.f, 0.f};
        if (flag[r]) {
            float4 mv = *(const float4*)&m_i[(size_t)r * 256 + cc];
            v[0] = mv.x; v[1] = mv.y; v[2] = mv.z; v[3] = mv.w;
        }
        int end = cursor[r];
        int start = (r == 0) ? 0 : cursor[r - 1];
        if (end > start) {
            int cs = start >> 4, ce = (end - 1) >> 4;
            for (int ch = cs; ch <= ce; ch++) {
                if (tag0[ch] == r) {
                    float4 s0 = *(const float4*)&msl0[(size_t)ch * 256 + cc];
                    v[0] += s0.x; v[1] += s0.y; v[2] += s0.z; v[3] += s0.w;
                }
                if (tag1[ch] == r) {
                    float4 s1 = *(const float4*)&msl1[(size_t)ch * 256 + cc];
                    v[0] += s1.x; v[1] += s1.y; v[2] += s1.z; v[3] += s1.w;
                }
            }
        }
        #pragma unroll
        for (int i = 0; i < 4; i++) m_is[rr * 264 + cc + i] = f2bf(v[i]);
        if (tid < 8) {
            int r2 = r0 + tid;
            float sx = 0.f, sy = 0.f, sz = 0.f;
            if (flag[r2]) {
                sx = x_agg[r2 * 3 + 0]; sy = x_agg[r2 * 3 + 1]; sz = x_agg[r2 * 3 + 2];
            }
            int end2 = cursor[r2];
            int start2 = (r2 == 0) ? 0 : cursor[r2 - 1];
            if (end2 > start2) {
                int cs2 = start2 >> 4, ce2 = (end2 - 1) >> 4;
                for (int ch = cs2; ch <= ce2; ch++) {
                    if (tag0[ch] == r2) { sx += xsl0[ch * 3 + 0]; sy += xsl0[ch * 3 + 1]; sz += xsl0[ch * 3 + 2]; }
                    if (tag1[ch] == r2) { sx += xsl1[ch * 3 + 0]; sy += xsl1[ch * 3 + 1]; sz += xsl1[ch * 3 + 2]; }
                }
            }
            x_cur[r2 * 3 + 0] += sx;
            x_cur[r2 * 3 + 1] += sy;
            x_cur[r2 * 3 + 2] += sz;
        }
    }
    __syncthreads();

    // ---- stage 1: t1 = silu([hc|m_i]@nW1+nb1), K=512; 32 cols/wave
    f32x4 acc[2];
    #pragma unroll
    for (int i = 0; i < 2; i++) acc[i] = (f32x4){0.f, 0.f, 0.f, 0.f};
    #pragma unroll 2
    for (int kt = 0; kt < 16; kt++) {
        int kk = kt * 32 + q * 8;
        short8 fa;
        if (kk < 256) fa = *(const short8*)&hc[(size_t)(r0 + alr) * 256 + kk];
        else          fa = *(const short8*)&m_is[alr * 264 + kk - 256];
        #pragma unroll
        for (int nt = 0; nt < 2; nt++) {
            short8 fb = *(const short8*)&wtN1[kt * 8192 + (wv * 32 + nt * 16 + lr) * 32 + q * 8];
            acc[nt] = __builtin_amdgcn_mfma_f32_16x16x32_bf16(fa, fb, acc[nt], 0, 0, 0);
        }
    }
    if (q < 2) {
        #pragma unroll
        for (int nt = 0; nt < 2; nt++) {
            int col = wv * 32 + nt * 16 + lr;
            float bv = nb1[col];
            #pragma unroll
            for (int rg = 0; rg < 4; rg++)
                t1s[(q * 4 + rg) * 264 + col] = f2bf_t(silu_f(acc[nt][rg] + bv));
        }
    }
    __syncthreads();

    // ---- stage 2: h' = hc + t1@nW2 + nb2 (32 cols/wave)
    f32x4 acc2[2];
    #pragma unroll
    for (int i = 0; i < 2; i++) acc2[i] = (f32x4){0.f, 0.f, 0.f, 0.f};
    #pragma unroll 2
    for (int kt = 0; kt < 8; kt++) {
        short8 fa = *(const short8*)&t1s[alr * 264 + kt * 32 + q * 8];
        #pragma unroll
        for (int nt = 0; nt < 2; nt++) {
            short8 fb = *(const short8*)&wtN2[kt * 8192 + (wv * 32 + nt * 16 + lr) * 32 + q * 8];
            acc2[nt] = __builtin_amdgcn_mfma_f32_16x16x32_bf16(fa, fb, acc2[nt], 0, 0, 0);
        }
    }
    if (q < 2) {
        #pragma unroll
        for (int nt = 0; nt < 2; nt++) {
            int col = wv * 32 + nt * 16 + lr;
            float bv = nb2[col];
            #pragma unroll
            for (int rg = 0; rg < 4; rg++) {
                int rrow = q * 4 + rg;
                float v = acc2[nt][rg] + bv + bf2f(hc[(size_t)(r0 + rrow) * 256 + col]);
                short b = f2bf(v);
                hn[(size_t)(r0 + rrow) * 256 + col] = b;
                h2s[rrow * 264 + col] = b;
            }
        }
    }
    __syncthreads();

    // ---- stage 3: P12 = h' @ AB (N=512, 64 cols/wave), +eb1_next on P1 half
    f32x4 acc3[4];
    #pragma unroll
    for (int i = 0; i < 4; i++) acc3[i] = (f32x4){0.f, 0.f, 0.f, 0.f};
    #pragma unroll 2
    for (int kt = 0; kt < 8; kt++) {
        short8 fa = *(const short8*)&h2s[alr * 264 + kt * 32 + q * 8];
        #pragma unroll
        for (int nt = 0; nt < 4; nt++) {
            short8 fb = *(const short8*)&wtAB[kt * 16384 + (wv * 64 + nt * 16 + lr) * 32 + q * 8];
            acc3[nt] = __builtin_amdgcn_mfma_f32_16x16x32_bf16(fa, fb, acc3[nt], 0, 0, 0);
        }
    }
    if (q < 2) {
        #pragma unroll
        for (int nt = 0; nt < 4; nt++) {
            int col = wv * 64 + nt * 16 + lr;
            float bv = (col < 256) ? eb1n[col] : 0.f;
            #pragma unroll
            for (int rg = 0; rg < 4; rg++)
                P12[(size_t)(r0 + q * 4 + rg) * 512 + col] = f2bf(acc3[nt][rg] + bv);
        }
    }
}

// ---------------------------------------------------------------- fused edge kernel (fp8)
// FROZEN from round 9/10 (60 µs; VALU 62% + MFMA 22% issue-bound).
// launch_bounds min-waves MUST stay 4 (8 caused a 1GB/dispatch VGPR spill).
__global__ __launch_bounds__(256, 4) void egnn_edge_mfma(
    const short* __restrict__ P12, const float* __restrict__ x,
    const int* __restrict__ prow, const int* __restrict__ pcol,
    const float* __restrict__ w512,
    const char* __restrict__ wf8E2, const float* __restrict__ eb2,
    const char* __restrict__ wf8C1, const float* __restrict__ cb1,
    const float* __restrict__ cW2,
    float* __restrict__ m_i, float* __restrict__ x_agg,
    float* __restrict__ msl0, float* __restrict__ msl1,
    float* __restrict__ xsl0, float* __restrict__ xsl1,
    int* __restrict__ tag0, int* __restrict__ tag1, int do_mi)
{
    __shared__ __align__(16) char m_lds[64 * 272];   // 17408 B, fp8
    __shared__ float cd_s[64][3];
    __shared__ int prow_s[64];
    __shared__ float wred[4][64];
    __shared__ float xtmp[64][3];

    int tid = threadIdx.x;
    int e0 = blockIdx.x * 64;
    int wv = tid >> 6, l = tid & 63;
    int lr = l & 15, q = l >> 4;

    // ---- phase 1 (no pre-barrier): m = silu(P1[r]+P2[c]+rad*w512) -> fp8 LDS
    {
        int e = tid >> 2, cq = tid & 3;
        int r = prow[e0 + e], c = pcol[e0 + e];
        float dx = x[r * 3 + 0] - x[c * 3 + 0];
        float dy = x[r * 3 + 1] - x[c * 3 + 1];
        float dz = x[r * 3 + 2] - x[c * 3 + 2];
        float rad = dx * dx + dy * dy + dz * dz;
        if (cq == 0) {
            prow_s[e] = r;
            cd_s[e][0] = dx; cd_s[e][1] = dy; cd_s[e][2] = dz;
        }
        const short* p1r = P12 + (size_t)r * 512;       // eb1 pre-folded into P1
        const short* p2r = P12 + (size_t)c * 512 + 256;
        #pragma unroll
        for (int j = 0; j < 8; j++) {
            int cb = (j >> 1) * 64 + (j & 1) * 32 + cq * 8;
            short8 a = *(const short8*)&p1r[cb];
            short8 b = *(const short8*)&p2r[cb];
            float4 w0 = *(const float4*)&w512[cb];
            float4 w1 = *(const float4*)&w512[cb + 4];
            float wv8[8] = {w0.x, w0.y, w0.z, w0.w, w1.x, w1.y, w1.z, w1.w};
            float s[8];
            #pragma unroll
            for (int k2 = 0; k2 < 8; k2++)
                s[k2] = silu_f(bf2f(a[k2]) + bf2f(b[k2]) + rad * wv8[k2]);
            int lo = __builtin_amdgcn_cvt_pk_fp8_f32(s[0], s[1], 0, false);
            lo = __builtin_amdgcn_cvt_pk_fp8_f32(s[2], s[3], lo, true);
            int hi = __builtin_amdgcn_cvt_pk_fp8_f32(s[4], s[5], 0, false);
            hi = __builtin_amdgcn_cvt_pk_fp8_f32(s[6], s[7], hi, true);
            int2 d = {lo, hi};
            *(int2*)&m_lds[e * 272 + cb] = d;
        }
    }
    __syncthreads();

    f32x4 acc[4][4];
    // ---- phase 2: m_ij = silu((m @ eW2)/16 + eb2)
    #pragma unroll
    for (int i = 0; i < 4; i++)
        #pragma unroll
        for (int j = 0; j < 4; j++) acc[i][j] = (f32x4){0.f, 0.f, 0.f, 0.f};
    #pragma unroll 2
    for (int kt = 0; kt < 8; kt++) {
        long fa[4], fb[4];
        #pragma unroll
        for (int mt = 0; mt < 4; mt++)
            fa[mt] = *(const long*)&m_lds[(mt * 16 + lr) * 272 + kt * 32 + q * 8];
        #pragma unroll
        for (int nt = 0; nt < 4; nt++)
            fb[nt] = *(const long*)&wf8E2[kt * 8192 + (wv * 64 + nt * 16 + lr) * 32 + q * 8];
        #pragma unroll
        for (int mt = 0; mt < 4; mt++)
            #pragma unroll
            for (int nt = 0; nt < 4; nt++)
                acc[mt][nt] = __builtin_amdgcn_mfma_f32_16x16x32_fp8_fp8(fa[mt], fb[nt], acc[mt][nt], 0, 0, 0);
    }
    __syncthreads();   // all fa reads done before overwrite
    #pragma unroll
    for (int nt = 0; nt < 4; nt++) {
        int ccol = wv * 64 + nt * 16 + lr;
        float b2 = eb2[ccol];
        #pragma unroll
        for (int mt = 0; mt < 4; mt++)
            #pragma unroll
            for (int rg = 0; rg < 4; rg++) {
                int e = mt * 16 + q * 4 + rg;
                float v = silu_f(fmaf(acc[mt][nt][rg], 0.0625f, b2));
                int p = __builtin_amdgcn_cvt_pk_fp8_f32(v, v, 0, false);
                m_lds[e * 272 + ccol] = (char)(p & 0xff);
            }
    }
    __syncthreads();

    // ---- phase 3: t3 = silu((m_ij @ cW1)/16 + cb1); w = t3 . cW2
    #pragma unroll
    for (int i = 0; i < 4; i++)
        #pragma unroll
        for (int j = 0; j < 4; j++) acc[i][j] = (f32x4){0.f, 0.f, 0.f, 0.f};
    #pragma unroll 2
    for (int kt = 0; kt < 8; kt++) {
        long fa[4], fb[4];
        #pragma unroll
        for (int mt = 0; mt < 4; mt++)
            fa[mt] = *(const long*)&m_lds[(mt * 16 + lr) * 272 + kt * 32 + q * 8];
        #pragma unroll
        for (int nt = 0; nt < 4; nt++)
            fb[nt] = *(const long*)&wf8C1[kt * 8192 + (wv * 64 + nt * 16 + lr) * 32 + q * 8];
        #pragma unroll
        for (int mt = 0; mt < 4; mt++)
            #pragma unroll
            for (int nt = 0; nt < 4; nt++)
                acc[mt][nt] = __builtin_amdgcn_mfma_f32_16x16x32_fp8_fp8(fa[mt], fb[nt], acc[mt][nt], 0, 0, 0);
    }

    // ---- m_i segment-sum (overlaps phase-3 MFMA drain)
    if (do_mi) {
        int ebase = wv * 16;
        int c4 = l * 4;
        int chunk = blockIdx.x * 4 + wv;
        float a0 = 0.f, a1 = 0.f, a2 = 0.f, a3 = 0.f;
        int cur = prow_s[ebase];
        int nrun = 0;
        #pragma unroll
        for (int j = 0; j < 16; j++) {
            int e = ebase + j;
            int r = prow_s[e];
            if (r != cur) {
                float4 v = {a0, a1, a2, a3};
                if (nrun == 0) *(float4*)&msl0[(size_t)chunk * 256 + c4] = v;
                else           *(float4*)&m_i[(size_t)cur * 256 + c4] = v;  // exclusive
                nrun++; a0 = a1 = a2 = a3 = 0.f; cur = r;
            }
            int mv = *(const int*)&m_lds[e * 272 + c4];
            f32x2 lo = __builtin_amdgcn_cvt_pk_f32_fp8(mv, false);
            f32x2 hi = __builtin_amdgcn_cvt_pk_f32_fp8(mv, true);
            a0 += lo.x; a1 += lo.y; a2 += hi.x; a3 += hi.y;
        }
        float4 v = {a0, a1, a2, a3};
        if (nrun == 0) *(float4*)&msl0[(size_t)chunk * 256 + c4] = v;
        else           *(float4*)&msl1[(size_t)chunk * 256 + c4] = v;
        if (l == 0) {
            tag0[chunk] = prow_s[ebase];
            tag1[chunk] = nrun ? cur : -1;
        }
    }

    // ---- epilogue 3: per-lane w partials, shuffle-reduce over 16 col-lanes
    {
        float wp[4][4];
        #pragma unroll
        for (int i = 0; i < 4; i++)
            #pragma unroll
            for (int j = 0; j < 4; j++) wp[i][j] = 0.f;
        #pragma unroll
        for (int nt = 0; nt < 4; nt++) {
            int ccol = wv * 64 + nt * 16 + lr;
            float b1 = cb1[ccol];
            float c2 = cW2[ccol];
            #pragma unroll
            for (int mt = 0; mt < 4; mt++)
                #pragma unroll
                for (int rg = 0; rg < 4; rg++)
                    wp[mt][rg] += silu_f(fmaf(acc[mt][nt][rg], 0.0625f, b1)) * c2;
        }
        #pragma unroll
        for (int mt = 0; mt < 4; mt++)
            #pragma unroll
            for (int rg = 0; rg < 4; rg++) {
                float v = wp[mt][rg];
                v += __shfl_xor(v, 1, 64);
                v += __shfl_xor(v, 2, 64);
                v += __shfl_xor(v, 4, 64);
                v += __shfl_xor(v, 8, 64);
                if (lr == 0) wred[wv][mt * 16 + q * 4 + rg] = v;
            }
    }
    __syncthreads();
    if (tid < 64) {
        float w = wred[0][tid] + wred[1][tid] + wred[2][tid] + wred[3][tid];
        xtmp[tid][0] = cd_s[tid][0] * w;
        xtmp[tid][1] = cd_s[tid][1] * w;
        xtmp[tid][2] = cd_s[tid][2] * w;
    }
    __syncthreads();
    if (tid < 64) {
        int e = tid, j = e & 15, cw = e >> 4;
        int r = prow_s[e];
        bool leader = (j == 0) || (prow_s[e - 1] != r);
        if (leader) {
            int eend = (cw + 1) * 16;
            float sx = 0.f, sy = 0.f, sz = 0.f;
            int k = e;
            while (k < eend && prow_s[k] == r) {
                sx += xtmp[k][0]; sy += xtmp[k][1]; sz += xtmp[k][2]; k++;
            }
            int chunk = blockIdx.x * 4 + cw;
            if (j == 0)        { xsl0[chunk * 3 + 0] = sx; xsl0[chunk * 3 + 1] = sy; xsl0[chunk * 3 + 2] = sz; }
            else if (k == eend){ xsl1[chunk * 3 + 0] = sx; xsl1[chunk * 3 + 1] = sy; xsl1[chunk * 3 + 2] = sz; }
            else               { x_agg[r * 3 + 0] = sx; x_agg[r * 3 + 1] = sy; x_agg[r * 3 + 2] = sz; }
        }
    }
}

// ---------------------------------------------------------------- loss (single kernel; out pre-zeroed in prep)
__global__ __launch_bounds__(256) void loss_part(
    const float* __restrict__ x_cur, const float* __restrict__ xt,
    const float* __restrict__ nc,
    const int* __restrict__ cursor, const int* __restrict__ flag,
    const int* __restrict__ tag0, const int* __restrict__ tag1,
    const float* __restrict__ xsl0, const float* __restrict__ xsl1,
    const float* __restrict__ x_agg,
    float* __restrict__ out)
{
    __shared__ float red[256];
    int b = blockIdx.x, a = threadIdx.x;
    int n = b * NA + a;
    int base = n * 3;

    // merge layer-3 x contributions
    float sx = 0.f, sy = 0.f, sz = 0.f;
    if (flag[n]) {
        sx = x_agg[base + 0]; sy = x_agg[base + 1]; sz = x_agg[base + 2];
    }
    int end = cursor[n];
    int start = (n == 0) ? 0 : cursor[n - 1];
    if (end > start) {
        int cs = start >> 4, ce = (end - 1) >> 4;
        for (int ch = cs; ch <= ce; ch++) {
            if (tag0[ch] == n) { sx += xsl0[ch * 3 + 0]; sy += xsl0[ch * 3 + 1]; sz += xsl0[ch * 3 + 2]; }
            if (tag1[ch] == n) { sx += xsl1[ch * 3 + 0]; sy += xsl1[ch * 3 + 1]; sz += xsl1[ch * 3 + 2]; }
        }
    }
    float px = x_cur[base + 0] + sx - xt[base + 0];
    float py = x_cur[base + 1] + sy - xt[base + 1];
    float pz = x_cur[base + 2] + sz - xt[base + 2];
    float mx = block_sum(px, red, a) * (1.f / NA);
    float my = block_sum(py, red, a) * (1.f / NA);
    float mz = block_sum(pz, red, a) * (1.f / NA);
    px -= mx; py -= my; pz -= mz;
    float dx = px - nc[base + 0], dy = py - nc[base + 1], dz = pz - nc[base + 2];
    float s = block_sum(dx * dx + dy * dy + dz * dz, red, a);
    if (a == 0) atomicAdd(out, s * (1.f / (float)(NNODES * 3)));
}

// ---------------------------------------------------------------- launch
extern "C" void kernel_launch(void* const* d_in, const int* in_sizes, int n_in,
                              void* d_out, int out_size, void* d_ws, size_t ws_size,
                              hipStream_t stream)
{
    (void)in_sizes; (void)n_in; (void)out_size; (void)ws_size;
    const float* h     = (const float*)d_in[0];
    const float* x0    = (const float*)d_in[1];
    const float* noise = (const float*)d_in[2];
    const int*   t     = (const int*)d_in[3];
    const int*   row   = (const int*)d_in[4];
    const int*   col   = (const int*)d_in[5];
    const float* W_emb = (const float*)d_in[6];
    const float* b_emb = (const float*)d_in[7];
    const float* eW1   = (const float*)d_in[8];
    const float* eb1   = (const float*)d_in[9];
    const float* eW2   = (const float*)d_in[10];
    const float* eb2   = (const float*)d_in[11];
    const float* cW1   = (const float*)d_in[12];
    const float* cb1   = (const float*)d_in[13];
    const float* cW2   = (const float*)d_in[14];
    const float* nW1   = (const float*)d_in[15];
    const float* nb1   = (const float*)d_in[16];
    const float* nW2   = (const float*)d_in[17];
    const float* nb2   = (const float*)d_in[18];

    // ---- workspace layout
    float* f = (float*)d_ws;
    size_t fo = 0;
    float* temb    = f + fo; fo += NB * TEMBD;
    float* noise_c = f + fo; fo += NNODES * 3;
    float* xt      = f + fo; fo += NNODES * 3;
    float* x_cur   = f + fo; fo += NNODES * 3;
    float* x_agg   = f + fo; fo += NNODES * 3;
    float* m_i     = f + fo; fo += (size_t)NNODES * HID;
    float* msl0    = f + fo; fo += (size_t)NCHUNK * 256;
    float* msl1    = f + fo; fo += (size_t)NCHUNK * 256;
    float* xsl0    = f + fo; fo += (size_t)NCHUNK * 3;
    float* xsl1    = f + fo; fo += (size_t)NCHUNK * 3;

    int* iw = (int*)(f + fo);
    size_t io = 0;
    int* deg    = iw + io; io += NNODES;
    int* cursor = iw + io; io += NNODES;
    int* flag   = iw + io; io += NNODES;
    int* prow   = iw + io; io += NE;
    int* pcol   = iw + io; io += NE;
    int* tag0   = iw + io; io += NCHUNK;
    int* tag1   = iw + io; io += NCHUNK;

    size_t sbase_bytes = ((((char*)(iw + io)) - (char*)d_ws) + 15) & ~(size_t)15;
    short* sb = (short*)((char*)d_ws + sbase_bytes);
    short* wb  = sb;
    size_t so = W_TOTAL;
    short* hh  = sb + so; so += (size_t)NNODES * HID;
    short* hh2 = sb + so; so += (size_t)NNODES * HID;
    short* P12 = sb + so; so += (size_t)NNODES * 512;
    char* wf8 = (char*)(sb + so);   // WF8_TOTAL bytes

    // ---- prologue (14 launches total)
    prep_kernel<<<NB, 256, 0, stream>>>(x0, noise, t, noise_c, xt, temb, deg, (float*)d_out, x_cur);
    csr_hist<<<NE / 256, 256, 0, stream>>>(row, deg);
    csr_scan<<<1, 256, 0, stream>>>(deg, cursor, flag);
    csr_scatter<<<NE / 256, 256, 0, stream>>>(row, col, cursor, prow, pcol);
    convert_weights<<<(W_TOTAL + WF8_TOTAL + 255) / 256, 256, 0, stream>>>(
        W_emb, eW1, eW2, cW1, nW1, nW2, wb, wf8);
    emb_p12_fused<<<NNODES / 8, 512, 0, stream>>>(
        h, temb, wb + WOFF_EMB, b_emb, wb + WOFF_L(0) + WOFF_AB, eb1, hh, P12);

    short* hc = hh;
    short* hn = hh2;
    for (int l = 0; l < NL; l++) {
        const short* wl = wb + WOFF_L(l);
        const char* wf8l = wf8 + (size_t)l * 131072;
        int last = (l == NL - 1);
        egnn_edge_mfma<<<NE / 64, 256, 0, stream>>>(
            P12, x_cur, prow, pcol,
            eW1 + (size_t)l * 513 * 256 + 512 * 256,
            wf8l, eb2 + (size_t)l * HID,
            wf8l + 65536, cb1 + (size_t)l * HID,
            cW2 + (size_t)l * HID,
            m_i, x_agg, msl0, msl1, xsl0, xsl1, tag0, tag1, last ? 0 : 1);
        if (!last) {
            node_p12_fused<<<NNODES / 8, 512, 0, stream>>>(
                hc, m_i, cursor, flag, tag0, tag1, msl0, msl1,
                xsl0, xsl1, x_agg, x_cur,
                wl + WOFF_N1, nb1 + (size_t)l * HID,
                wl + WOFF_N2, nb2 + (size_t)l * HID,
                wb + WOFF_L(l + 1) + WOFF_AB, eb1 + (size_t)(l + 1) * HID,
                hn, P12);
            short* tmp = hc; hc = hn; hn = tmp;
        }
    }

    loss_part<<<NB, 256, 0, stream>>>(
        x_cur, xt, noise_c, cursor, flag, tag0, tag1, xsl0, xsl1, x_agg, (float*)d_out);
}

// Round 12
// 435.154 us; speedup vs baseline: 1.0762x; 1.0762x over previous
//
#include <hip/hip_runtime.h>

#define NB 16
#define NA 256
#define NNODES 4096
#define FEATD 64
#define HID 256
#define TEMBD 32
#define NUMT 100
#define NE 131072
#define NL 4
#define NCHUNK (NE / 16)   // 8192 16-edge chunks

typedef __attribute__((ext_vector_type(8))) short short8;
typedef __attribute__((ext_vector_type(4))) float f32x4;
typedef __attribute__((ext_vector_type(2))) float f32x2;

// fast silu: v * rcp(1 + exp2(-log2e * v))
__device__ __forceinline__ float silu_f(float v) {
    float s = __builtin_amdgcn_rcpf(1.f + __builtin_amdgcn_exp2f(-1.44269504f * v));
    return v * s;
}

__device__ __forceinline__ short f2bf(float f) {          // RNE
    union { float f; unsigned u; } v; v.f = f;
    unsigned r = (v.u + 0x7fffu + ((v.u >> 16) & 1u)) >> 16;
    return (short)r;
}
__device__ __forceinline__ short f2bf_t(float f) {        // truncate (intermediates)
    union { float f; unsigned u; } v; v.f = f;
    return (short)(v.u >> 16);
}
__device__ __forceinline__ float bf2f(short s) {
    union { float f; unsigned u; } v; v.u = ((unsigned)(unsigned short)s) << 16;
    return v.f;
}

__device__ __forceinline__ float block_sum(float v, float* red, int a) {
    red[a] = v; __syncthreads();
    for (int s = 128; s > 0; s >>= 1) {
        if (a < s) red[a] += red[a + s];
        __syncthreads();
    }
    float r = red[0]; __syncthreads();
    return r;
}

// ---------------------------------------------------------------- prep (+deg zero, +out zero, +x_cur init)
__global__ __launch_bounds__(256) void prep_kernel(
    const float* __restrict__ x0, const float* __restrict__ noise,
    const int* __restrict__ t,
    float* __restrict__ noise_c, float* __restrict__ xt, float* __restrict__ temb,
    int* __restrict__ deg, float* __restrict__ out, float* __restrict__ x_cur)
{
    __shared__ float red[256];
    __shared__ float sab_s[2];
    int b = blockIdx.x, a = threadIdx.x;
    int base = (b * NA + a) * 3;

    deg[b * 256 + a] = 0;
    if (b == 0 && a == 0) out[0] = 0.f;

    float nx = noise[base + 0], ny = noise[base + 1], nz = noise[base + 2];
    float mnx = block_sum(nx, red, a) * (1.f / NA);
    float mny = block_sum(ny, red, a) * (1.f / NA);
    float mnz = block_sum(nz, red, a) * (1.f / NA);
    nx -= mnx; ny -= mny; nz -= mnz;
    noise_c[base + 0] = nx; noise_c[base + 1] = ny; noise_c[base + 2] = nz;

    if (a == 0) {
        int tt = t[b];
        float p = 1.f;
        for (int i = 0; i < NUMT; i++) {
            float beta = 1e-4f + (0.02f - 1e-4f) * (float)i / (float)(NUMT - 1);
            if (i <= tt) p *= (1.f - beta);
        }
        sab_s[0] = sqrtf(p);
        sab_s[1] = sqrtf(1.f - p);
    }
    __syncthreads();
    float sab = sab_s[0], s1ab = sab_s[1];

    float xx = sab * x0[base + 0] + s1ab * nx;
    float xy = sab * x0[base + 1] + s1ab * ny;
    float xz = sab * x0[base + 2] + s1ab * nz;
    float mx = block_sum(xx, red, a) * (1.f / NA);
    float my = block_sum(xy, red, a) * (1.f / NA);
    float mz = block_sum(xz, red, a) * (1.f / NA);
    float vx = xx - mx, vy = xy - my, vz = xz - mz;
    xt[base + 0] = vx; xt[base + 1] = vy; xt[base + 2] = vz;
    x_cur[base + 0] = vx; x_cur[base + 1] = vy; x_cur[base + 2] = vz;

    if (a < TEMBD / 2) {
        float fr = expf(-logf(10000.f) * (float)a / (float)(TEMBD / 2 - 1));
        float ang = (float)t[b] * fr;
        temb[b * TEMBD + a] = sinf(ang);
        temb[b * TEMBD + TEMBD / 2 + a] = cosf(ang);
    }
}

// ---------------------------------------------------------------- CSR build
__global__ __launch_bounds__(256) void csr_hist(const int* __restrict__ row, int* __restrict__ deg)
{
    int i = blockIdx.x * 256 + threadIdx.x;
    if (i < NE) atomicAdd(&deg[row[i]], 1);
}

// scan + flag fused: cursor[r] = exclusive start offset; flag[r] = row has an
// interior run in some 16-edge chunk (direct m_i/x_agg store exists).
__global__ __launch_bounds__(256) void csr_scan(
    const int* __restrict__ deg, int* __restrict__ cursor, int* __restrict__ flag)
{
    __shared__ int s[256];
    int t = threadIdx.x;
    int base = t * 16;
    int loc[16], dg[16];
    int sum = 0;
    for (int i = 0; i < 16; i++) { dg[i] = deg[base + i]; loc[i] = sum; sum += dg[i]; }
    s[t] = sum; __syncthreads();
    for (int off = 1; off < 256; off <<= 1) {
        int v = (t >= off) ? s[t - off] : 0;
        __syncthreads();
        s[t] += v;
        __syncthreads();
    }
    int excl = (t == 0) ? 0 : s[t - 1];
    for (int i = 0; i < 16; i++) {
        int start = excl + loc[i];
        cursor[base + i] = start;
        int end = start + dg[i];
        int fl = 0;
        if (end > start) {
            int cs = start >> 4, ce = (end - 1) >> 4;
            for (int ch = cs; ch <= ce; ch++) {
                int rs = start > ch * 16 ? start : ch * 16;
                int re = end < ch * 16 + 16 ? end : ch * 16 + 16;
                if (rs > ch * 16 && re < ch * 16 + 16) fl = 1;
            }
        }
        flag[base + i] = fl;
    }
}

__global__ __launch_bounds__(256) void csr_scatter(
    const int* __restrict__ row, const int* __restrict__ col,
    int* __restrict__ cursor, int* __restrict__ prow, int* __restrict__ pcol)
{
    int i = blockIdx.x * 256 + threadIdx.x;
    if (i < NE) {
        int r = row[i];
        int p = atomicAdd(&cursor[r], 1);
        prow[p] = r;
        pcol[p] = col[i];
    }
}

// ---------------------------------------------------------------- weight convert (bf16 + fp8, one kernel)
// bf16 layout per weight: [kt][n(N)][kk(32)]
#define WOFF_EMB 0
#define WOFF_L(l) (24576 + (l) * 458752)
#define WOFF_AB 0
#define WOFF_E2 131072
#define WOFF_C1 196608
#define WOFF_N1 262144
#define WOFF_N2 393216
#define W_TOTAL (24576 + 4 * 458752)
#define WF8_TOTAL (4 * 2 * 65536)

__global__ __launch_bounds__(256) void convert_weights(
    const float* __restrict__ W_emb, const float* __restrict__ eW1,
    const float* __restrict__ eW2, const float* __restrict__ cW1,
    const float* __restrict__ nW1, const float* __restrict__ nW2,
    short* __restrict__ wb, char* __restrict__ wf8)
{
    int idx = blockIdx.x * 256 + threadIdx.x;
    if (idx >= W_TOTAL) {
        // fp8 e4m3 (x16 scaled) edge weights: [l][mat(E2,C1)][kt][n(256)][kk(32)]
        int i8 = idx - W_TOTAL;
        if (i8 >= WF8_TOTAL) return;
        int l = i8 >> 17;
        int o = i8 & 131071;
        int mat = o >> 16;
        int o2 = o & 65535;
        int k = o2 >> 8, n = o2 & 255;
        const float* src = (mat == 0 ? eW2 : cW1) + (size_t)l * 65536 + (size_t)k * 256 + n;
        float v = (*src) * 16.f;
        int p = __builtin_amdgcn_cvt_pk_fp8_f32(v, v, 0, false);
        wf8[(size_t)l * 131072 + mat * 65536 + (k >> 5) * 8192 + n * 32 + (k & 31)] = (char)(p & 0xff);
        return;
    }
    if (idx < 24576) {
        int k = idx >> 8, n = idx & 255;
        wb[WOFF_EMB + ((k >> 5) << 13) + (n << 5) + (k & 31)] = f2bf(W_emb[idx]);
        return;
    }
    int r = idx - 24576;
    int l = r / 458752;
    int o = r - l * 458752;
    if (o < 131072) {
        int k = o >> 9, n = o & 511;
        const float* src = eW1 + (size_t)l * 513 * 256 +
            (n < 256 ? (size_t)k * 256 + n : (size_t)(256 + k) * 256 + (n - 256));
        wb[WOFF_L(l) + WOFF_AB + ((k >> 5) * 16384) + (n << 5) + (k & 31)] = f2bf(*src);
        return;
    }
    const float* src; int dst; int o2;
    if (o < 196608)      { o2 = o - 131072; src = eW2 + (size_t)l * 65536 + o2;  dst = WOFF_L(l) + WOFF_E2; }
    else if (o < 262144) { o2 = o - 196608; src = cW1 + (size_t)l * 65536 + o2;  dst = WOFF_L(l) + WOFF_C1; }
    else if (o < 393216) { o2 = o - 262144; src = nW1 + (size_t)l * 131072 + o2; dst = WOFF_L(l) + WOFF_N1; }
    else                 { o2 = o - 393216; src = nW2 + (size_t)l * 65536 + o2;  dst = WOFF_L(l) + WOFF_N2; }
    int k = o2 >> 8, n = o2 & 255;
    wb[dst + ((k >> 5) << 13) + (n << 5) + (k & 31)] = f2bf(*src);
}

// ---------------------------------------------------------------- emb GEMM + layer0 P12 fused
// ROUND-10 geometry (measured best): 16 nodes/block, 1024 threads, grid 256.
__global__ __launch_bounds__(1024) void emb_p12_fused(
    const float* __restrict__ h, const float* __restrict__ temb,
    const short* __restrict__ wtEmb,
    const float* __restrict__ b_emb, const short* __restrict__ wtAB,
    const float* __restrict__ eb1_0,
    short* __restrict__ hh, short* __restrict__ P12)
{
    __shared__ short h2s[16 * 264];
    int tid = threadIdx.x;
    int wv = tid >> 6, l = tid & 63;
    int lr = l & 15, q = l >> 4;
    int r0 = blockIdx.x * 16;

    // ---- stage A: hh = [h|temb] @ W_emb + b (K=96, 16 cols/wave)
    f32x4 acc = (f32x4){0.f, 0.f, 0.f, 0.f};
    int col0 = wv * 16 + lr;
    int n = r0 + lr;
    #pragma unroll
    for (int kt = 0; kt < 3; kt++) {
        int kk = kt * 32 + q * 8;
        const float* src = (kk < 64) ? &h[(size_t)n * 64 + kk]
                                     : &temb[(n >> 8) * 32 + kk - 64];
        short8 fa;
        #pragma unroll
        for (int k2 = 0; k2 < 8; k2++) fa[k2] = f2bf(src[k2]);
        short8 fb = *(const short8*)&wtEmb[kt * 8192 + col0 * 32 + q * 8];
        acc = __builtin_amdgcn_mfma_f32_16x16x32_bf16(fa, fb, acc, 0, 0, 0);
    }
    {
        float bv = b_emb[col0];
        #pragma unroll
        for (int rg = 0; rg < 4; rg++) {
            int rrow = q * 4 + rg;
            short b = f2bf(acc[rg] + bv);
            hh[(size_t)(r0 + rrow) * 256 + col0] = b;
            h2s[rrow * 264 + col0] = b;
        }
    }
    __syncthreads();

    // ---- stage B: P12 = hh @ AB (N=512, 32 cols/wave), +eb1_0 on P1 half
    f32x4 acc3[2];
    #pragma unroll
    for (int i = 0; i < 2; i++) acc3[i] = (f32x4){0.f, 0.f, 0.f, 0.f};
    #pragma unroll 2
    for (int kt = 0; kt < 8; kt++) {
        short8 fa = *(const short8*)&h2s[lr * 264 + kt * 32 + q * 8];
        #pragma unroll
        for (int nt = 0; nt < 2; nt++) {
            short8 fb = *(const short8*)&wtAB[kt * 16384 + (wv * 32 + nt * 16 + lr) * 32 + q * 8];
            acc3[nt] = __builtin_amdgcn_mfma_f32_16x16x32_bf16(fa, fb, acc3[nt], 0, 0, 0);
        }
    }
    #pragma unroll
    for (int nt = 0; nt < 2; nt++) {
        int col = wv * 32 + nt * 16 + lr;
        float bv = (col < 256) ? eb1_0[col] : 0.f;
        #pragma unroll
        for (int rg = 0; rg < 4; rg++)
            P12[(size_t)(r0 + q * 4 + rg) * 512 + col] = f2bf(acc3[nt][rg] + bv);
    }
}

// ---------------------------------------------------------------- node MLP + next P12
// ROUND-10 geometry (measured best): 16 nodes/block, 1024 threads, grid 256.
__global__ __launch_bounds__(1024) void node_p12_fused(
    const short* __restrict__ hc, const float* __restrict__ m_i,
    const int* __restrict__ cursor, const int* __restrict__ flag,
    const int* __restrict__ tag0, const int* __restrict__ tag1,
    const float* __restrict__ msl0, const float* __restrict__ msl1,
    const float* __restrict__ xsl0, const float* __restrict__ xsl1,
    const float* __restrict__ x_agg, float* __restrict__ x_cur,
    const short* __restrict__ wtN1, const float* __restrict__ nb1,
    const short* __restrict__ wtN2, const float* __restrict__ nb2,
    const short* __restrict__ wtAB, const float* __restrict__ eb1n,
    short* __restrict__ hn, short* __restrict__ P12)
{
    __shared__ short m_is[16 * 264];
    __shared__ short t1s[16 * 264];
    __shared__ short h2s[16 * 264];
    int tid = threadIdx.x;
    int wv = tid >> 6, l = tid & 63;
    int lr = l & 15, q = l >> 4;
    int r0 = blockIdx.x * 16;

    // ---- stage 0: m_i slot-merge -> LDS bf16 (4 cols/thread); x merge (tid<16)
    {
        int rr = tid >> 6;              // 0..15
        int cc = (tid & 63) * 4;        // 4 cols per thread
        int r = r0 + rr;
        float v[4] = {0.f, 0.f, 0.f, 0.f};
        if (flag[r]) {
            float4 mv = *(const float4*)&m_i[(size_t)r * 256 + cc];
            v[0] = mv.x; v[1] = mv.y; v[2] = mv.z; v[3] = mv.w;
        }
        int end = cursor[r];
        int start = (r == 0) ? 0 : cursor[r - 1];
        if (end > start) {
            int cs = start >> 4, ce = (end - 1) >> 4;
            for (int ch = cs; ch <= ce; ch++) {
                if (tag0[ch] == r) {
                    float4 s0 = *(const float4*)&msl0[(size_t)ch * 256 + cc];
                    v[0] += s0.x; v[1] += s0.y; v[2] += s0.z; v[3] += s0.w;
                }
                if (tag1[ch] == r) {
                    float4 s1 = *(const float4*)&msl1[(size_t)ch * 256 + cc];
                    v[0] += s1.x; v[1] += s1.y; v[2] += s1.z; v[3] += s1.w;
                }
            }
        }
        #pragma unroll
        for (int i = 0; i < 4; i++) m_is[rr * 264 + cc + i] = f2bf(v[i]);
        if (tid < 16) {
            int r2 = r0 + tid;
            float sx = 0.f, sy = 0.f, sz = 0.f;
            if (flag[r2]) {
                sx = x_agg[r2 * 3 + 0]; sy = x_agg[r2 * 3 + 1]; sz = x_agg[r2 * 3 + 2];
            }
            int end2 = cursor[r2];
            int start2 = (r2 == 0) ? 0 : cursor[r2 - 1];
            if (end2 > start2) {
                int cs2 = start2 >> 4, ce2 = (end2 - 1) >> 4;
                for (int ch = cs2; ch <= ce2; ch++) {
                    if (tag0[ch] == r2) { sx += xsl0[ch * 3 + 0]; sy += xsl0[ch * 3 + 1]; sz += xsl0[ch * 3 + 2]; }
                    if (tag1[ch] == r2) { sx += xsl1[ch * 3 + 0]; sy += xsl1[ch * 3 + 1]; sz += xsl1[ch * 3 + 2]; }
                }
            }
            x_cur[r2 * 3 + 0] += sx;
            x_cur[r2 * 3 + 1] += sy;
            x_cur[r2 * 3 + 2] += sz;
        }
    }
    __syncthreads();

    // ---- stage 1: t1 = silu([hc|m_i]@nW1+nb1), K=512; 16 cols/wave
    int col0 = wv * 16 + lr;
    f32x4 acc = (f32x4){0.f, 0.f, 0.f, 0.f};
    #pragma unroll 2
    for (int kt = 0; kt < 16; kt++) {
        int kk = kt * 32 + q * 8;
        short8 fa;
        if (kk < 256) fa = *(const short8*)&hc[(size_t)(r0 + lr) * 256 + kk];
        else          fa = *(const short8*)&m_is[lr * 264 + kk - 256];
        short8 fb = *(const short8*)&wtN1[kt * 8192 + col0 * 32 + q * 8];
        acc = __builtin_amdgcn_mfma_f32_16x16x32_bf16(fa, fb, acc, 0, 0, 0);
    }
    {
        float bv = nb1[col0];
        #pragma unroll
        for (int rg = 0; rg < 4; rg++)
            t1s[(q * 4 + rg) * 264 + col0] = f2bf_t(silu_f(acc[rg] + bv));
    }
    __syncthreads();

    // ---- stage 2: h' = hc + t1@nW2 + nb2 (16 cols/wave)
    f32x4 acc2 = (f32x4){0.f, 0.f, 0.f, 0.f};
    #pragma unroll 2
    for (int kt = 0; kt < 8; kt++) {
        short8 fa = *(const short8*)&t1s[lr * 264 + kt * 32 + q * 8];
        short8 fb = *(const short8*)&wtN2[kt * 8192 + col0 * 32 + q * 8];
        acc2 = __builtin_amdgcn_mfma_f32_16x16x32_bf16(fa, fb, acc2, 0, 0, 0);
    }
    {
        float bv = nb2[col0];
        #pragma unroll
        for (int rg = 0; rg < 4; rg++) {
            int rrow = q * 4 + rg;
            float v = acc2[rg] + bv + bf2f(hc[(size_t)(r0 + rrow) * 256 + col0]);
            short b = f2bf(v);
            hn[(size_t)(r0 + rrow) * 256 + col0] = b;
            h2s[rrow * 264 + col0] = b;
        }
    }
    __syncthreads();

    // ---- stage 3: P12 = h' @ AB (N=512, 32 cols/wave), +eb1_next on P1 half
    f32x4 acc3[2];
    #pragma unroll
    for (int i = 0; i < 2; i++) acc3[i] = (f32x4){0.f, 0.f, 0.f, 0.f};
    #pragma unroll 2
    for (int kt = 0; kt < 8; kt++) {
        short8 fa = *(const short8*)&h2s[lr * 264 + kt * 32 + q * 8];
        #pragma unroll
        for (int nt = 0; nt < 2; nt++) {
            short8 fb = *(const short8*)&wtAB[kt * 16384 + (wv * 32 + nt * 16 + lr) * 32 + q * 8];
            acc3[nt] = __builtin_amdgcn_mfma_f32_16x16x32_bf16(fa, fb, acc3[nt], 0, 0, 0);
        }
    }
    #pragma unroll
    for (int nt = 0; nt < 2; nt++) {
        int col = wv * 32 + nt * 16 + lr;
        float bv = (col < 256) ? eb1n[col] : 0.f;
        #pragma unroll
        for (int rg = 0; rg < 4; rg++)
            P12[(size_t)(r0 + q * 4 + rg) * 512 + col] = f2bf(acc3[nt][rg] + bv);
    }
}

// ---------------------------------------------------------------- fused edge kernel (fp8)
// FROZEN (60 µs; VALU 62% + MFMA 22% issue-bound).
// launch_bounds min-waves MUST stay 4 (8 caused a 1GB/dispatch VGPR spill).
__global__ __launch_bounds__(256, 4) void egnn_edge_mfma(
    const short* __restrict__ P12, const float* __restrict__ x,
    const int* __restrict__ prow, const int* __restrict__ pcol,
    const float* __restrict__ w512,
    const char* __restrict__ wf8E2, const float* __restrict__ eb2,
    const char* __restrict__ wf8C1, const float* __restrict__ cb1,
    const float* __restrict__ cW2,
    float* __restrict__ m_i, float* __restrict__ x_agg,
    float* __restrict__ msl0, float* __restrict__ msl1,
    float* __restrict__ xsl0, float* __restrict__ xsl1,
    int* __restrict__ tag0, int* __restrict__ tag1, int do_mi)
{
    __shared__ __align__(16) char m_lds[64 * 272];   // 17408 B, fp8
    __shared__ float cd_s[64][3];
    __shared__ int prow_s[64];
    __shared__ float wred[4][64];
    __shared__ float xtmp[64][3];

    int tid = threadIdx.x;
    int e0 = blockIdx.x * 64;
    int wv = tid >> 6, l = tid & 63;
    int lr = l & 15, q = l >> 4;

    // ---- phase 1 (no pre-barrier): m = silu(P1[r]+P2[c]+rad*w512) -> fp8 LDS
    {
        int e = tid >> 2, cq = tid & 3;
        int r = prow[e0 + e], c = pcol[e0 + e];
        float dx = x[r * 3 + 0] - x[c * 3 + 0];
        float dy = x[r * 3 + 1] - x[c * 3 + 1];
        float dz = x[r * 3 + 2] - x[c * 3 + 2];
        float rad = dx * dx + dy * dy + dz * dz;
        if (cq == 0) {
            prow_s[e] = r;
            cd_s[e][0] = dx; cd_s[e][1] = dy; cd_s[e][2] = dz;
        }
        const short* p1r = P12 + (size_t)r * 512;       // eb1 pre-folded into P1
        const short* p2r = P12 + (size_t)c * 512 + 256;
        #pragma unroll
        for (int j = 0; j < 8; j++) {
            int cb = (j >> 1) * 64 + (j & 1) * 32 + cq * 8;
            short8 a = *(const short8*)&p1r[cb];
            short8 b = *(const short8*)&p2r[cb];
            float4 w0 = *(const float4*)&w512[cb];
            float4 w1 = *(const float4*)&w512[cb + 4];
            float wv8[8] = {w0.x, w0.y, w0.z, w0.w, w1.x, w1.y, w1.z, w1.w};
            float s[8];
            #pragma unroll
            for (int k2 = 0; k2 < 8; k2++)
                s[k2] = silu_f(bf2f(a[k2]) + bf2f(b[k2]) + rad * wv8[k2]);
            int lo = __builtin_amdgcn_cvt_pk_fp8_f32(s[0], s[1], 0, false);
            lo = __builtin_amdgcn_cvt_pk_fp8_f32(s[2], s[3], lo, true);
            int hi = __builtin_amdgcn_cvt_pk_fp8_f32(s[4], s[5], 0, false);
            hi = __builtin_amdgcn_cvt_pk_fp8_f32(s[6], s[7], hi, true);
            int2 d = {lo, hi};
            *(int2*)&m_lds[e * 272 + cb] = d;
        }
    }
    __syncthreads();

    f32x4 acc[4][4];
    // ---- phase 2: m_ij = silu((m @ eW2)/16 + eb2)
    #pragma unroll
    for (int i = 0; i < 4; i++)
        #pragma unroll
        for (int j = 0; j < 4; j++) acc[i][j] = (f32x4){0.f, 0.f, 0.f, 0.f};
    #pragma unroll 2
    for (int kt = 0; kt < 8; kt++) {
        long fa[4], fb[4];
        #pragma unroll
        for (int mt = 0; mt < 4; mt++)
            fa[mt] = *(const long*)&m_lds[(mt * 16 + lr) * 272 + kt * 32 + q * 8];
        #pragma unroll
        for (int nt = 0; nt < 4; nt++)
            fb[nt] = *(const long*)&wf8E2[kt * 8192 + (wv * 64 + nt * 16 + lr) * 32 + q * 8];
        #pragma unroll
        for (int mt = 0; mt < 4; mt++)
            #pragma unroll
            for (int nt = 0; nt < 4; nt++)
                acc[mt][nt] = __builtin_amdgcn_mfma_f32_16x16x32_fp8_fp8(fa[mt], fb[nt], acc[mt][nt], 0, 0, 0);
    }
    __syncthreads();   // all fa reads done before overwrite
    #pragma unroll
    for (int nt = 0; nt < 4; nt++) {
        int ccol = wv * 64 + nt * 16 + lr;
        float b2 = eb2[ccol];
        #pragma unroll
        for (int mt = 0; mt < 4; mt++)
            #pragma unroll
            for (int rg = 0; rg < 4; rg++) {
                int e = mt * 16 + q * 4 + rg;
                float v = silu_f(fmaf(acc[mt][nt][rg], 0.0625f, b2));
                int p = __builtin_amdgcn_cvt_pk_fp8_f32(v, v, 0, false);
                m_lds[e * 272 + ccol] = (char)(p & 0xff);
            }
    }
    __syncthreads();

    // ---- phase 3: t3 = silu((m_ij @ cW1)/16 + cb1); w = t3 . cW2
    #pragma unroll
    for (int i = 0; i < 4; i++)
        #pragma unroll
        for (int j = 0; j < 4; j++) acc[i][j] = (f32x4){0.f, 0.f, 0.f, 0.f};
    #pragma unroll 2
    for (int kt = 0; kt < 8; kt++) {
        long fa[4], fb[4];
        #pragma unroll
        for (int mt = 0; mt < 4; mt++)
            fa[mt] = *(const long*)&m_lds[(mt * 16 + lr) * 272 + kt * 32 + q * 8];
        #pragma unroll
        for (int nt = 0; nt < 4; nt++)
            fb[nt] = *(const long*)&wf8C1[kt * 8192 + (wv * 64 + nt * 16 + lr) * 32 + q * 8];
        #pragma unroll
        for (int mt = 0; mt < 4; mt++)
            #pragma unroll
            for (int nt = 0; nt < 4; nt++)
                acc[mt][nt] = __builtin_amdgcn_mfma_f32_16x16x32_fp8_fp8(fa[mt], fb[nt], acc[mt][nt], 0, 0, 0);
    }

    // ---- m_i segment-sum (overlaps phase-3 MFMA drain)
    if (do_mi) {
        int ebase = wv * 16;
        int c4 = l * 4;
        int chunk = blockIdx.x * 4 + wv;
        float a0 = 0.f, a1 = 0.f, a2 = 0.f, a3 = 0.f;
        int cur = prow_s[ebase];
        int nrun = 0;
        #pragma unroll
        for (int j = 0; j < 16; j++) {
            int e = ebase + j;
            int r = prow_s[e];
            if (r != cur) {
                float4 v = {a0, a1, a2, a3};
                if (nrun == 0) *(float4*)&msl0[(size_t)chunk * 256 + c4] = v;
                else           *(float4*)&m_i[(size_t)cur * 256 + c4] = v;  // exclusive
                nrun++; a0 = a1 = a2 = a3 = 0.f; cur = r;
            }
            int mv = *(const int*)&m_lds[e * 272 + c4];
            f32x2 lo = __builtin_amdgcn_cvt_pk_f32_fp8(mv, false);
            f32x2 hi = __builtin_amdgcn_cvt_pk_f32_fp8(mv, true);
            a0 += lo.x; a1 += lo.y; a2 += hi.x; a3 += hi.y;
        }
        float4 v = {a0, a1, a2, a3};
        if (nrun == 0) *(float4*)&msl0[(size_t)chunk * 256 + c4] = v;
        else           *(float4*)&msl1[(size_t)chunk * 256 + c4] = v;
        if (l == 0) {
            tag0[chunk] = prow_s[ebase];
            tag1[chunk] = nrun ? cur : -1;
        }
    }

    // ---- epilogue 3: per-lane w partials, shuffle-reduce over 16 col-lanes
    {
        float wp[4][4];
        #pragma unroll
        for (int i = 0; i < 4; i++)
            #pragma unroll
            for (int j = 0; j < 4; j++) wp[i][j] = 0.f;
        #pragma unroll
        for (int nt = 0; nt < 4; nt++) {
            int ccol = wv * 64 + nt * 16 + lr;
            float b1 = cb1[ccol];
            float c2 = cW2[ccol];
            #pragma unroll
            for (int mt = 0; mt < 4; mt++)
                #pragma unroll
                for (int rg = 0; rg < 4; rg++)
                    wp[mt][rg] += silu_f(fmaf(acc[mt][nt][rg], 0.0625f, b1)) * c2;
        }
        #pragma unroll
        for (int mt = 0; mt < 4; mt++)
            #pragma unroll
            for (int rg = 0; rg < 4; rg++) {
                float v = wp[mt][rg];
                v += __shfl_xor(v, 1, 64);
                v += __shfl_xor(v, 2, 64);
                v += __shfl_xor(v, 4, 64);
                v += __shfl_xor(v, 8, 64);
                if (lr == 0) wred[wv][mt * 16 + q * 4 + rg] = v;
            }
    }
    __syncthreads();
    if (tid < 64) {
        float w = wred[0][tid] + wred[1][tid] + wred[2][tid] + wred[3][tid];
        xtmp[tid][0] = cd_s[tid][0] * w;
        xtmp[tid][1] = cd_s[tid][1] * w;
        xtmp[tid][2] = cd_s[tid][2] * w;
    }
    __syncthreads();
    if (tid < 64) {
        int e = tid, j = e & 15, cw = e >> 4;
        int r = prow_s[e];
        bool leader = (j == 0) || (prow_s[e - 1] != r);
        if (leader) {
            int eend = (cw + 1) * 16;
            float sx = 0.f, sy = 0.f, sz = 0.f;
            int k = e;
            while (k < eend && prow_s[k] == r) {
                sx += xtmp[k][0]; sy += xtmp[k][1]; sz += xtmp[k][2]; k++;
            }
            int chunk = blockIdx.x * 4 + cw;
            if (j == 0)        { xsl0[chunk * 3 + 0] = sx; xsl0[chunk * 3 + 1] = sy; xsl0[chunk * 3 + 2] = sz; }
            else if (k == eend){ xsl1[chunk * 3 + 0] = sx; xsl1[chunk * 3 + 1] = sy; xsl1[chunk * 3 + 2] = sz; }
            else               { x_agg[r * 3 + 0] = sx; x_agg[r * 3 + 1] = sy; x_agg[r * 3 + 2] = sz; }
        }
    }
}

// ---------------------------------------------------------------- loss (single kernel; out pre-zeroed in prep)
__global__ __launch_bounds__(256) void loss_part(
    const float* __restrict__ x_cur, const float* __restrict__ xt,
    const float* __restrict__ nc,
    const int* __restrict__ cursor, const int* __restrict__ flag,
    const int* __restrict__ tag0, const int* __restrict__ tag1,
    const float* __restrict__ xsl0, const float* __restrict__ xsl1,
    const float* __restrict__ x_agg,
    float* __restrict__ out)
{
    __shared__ float red[256];
    int b = blockIdx.x, a = threadIdx.x;
    int n = b * NA + a;
    int base = n * 3;

    // merge layer-3 x contributions
    float sx = 0.f, sy = 0.f, sz = 0.f;
    if (flag[n]) {
        sx = x_agg[base + 0]; sy = x_agg[base + 1]; sz = x_agg[base + 2];
    }
    int end = cursor[n];
    int start = (n == 0) ? 0 : cursor[n - 1];
    if (end > start) {
        int cs = start >> 4, ce = (end - 1) >> 4;
        for (int ch = cs; ch <= ce; ch++) {
            if (tag0[ch] == n) { sx += xsl0[ch * 3 + 0]; sy += xsl0[ch * 3 + 1]; sz += xsl0[ch * 3 + 2]; }
            if (tag1[ch] == n) { sx += xsl1[ch * 3 + 0]; sy += xsl1[ch * 3 + 1]; sz += xsl1[ch * 3 + 2]; }
        }
    }
    float px = x_cur[base + 0] + sx - xt[base + 0];
    float py = x_cur[base + 1] + sy - xt[base + 1];
    float pz = x_cur[base + 2] + sz - xt[base + 2];
    float mx = block_sum(px, red, a) * (1.f / NA);
    float my = block_sum(py, red, a) * (1.f / NA);
    float mz = block_sum(pz, red, a) * (1.f / NA);
    px -= mx; py -= my; pz -= mz;
    float dx = px - nc[base + 0], dy = py - nc[base + 1], dz = pz - nc[base + 2];
    float s = block_sum(dx * dx + dy * dy + dz * dz, red, a);
    if (a == 0) atomicAdd(out, s * (1.f / (float)(NNODES * 3)));
}

// ---------------------------------------------------------------- launch
extern "C" void kernel_launch(void* const* d_in, const int* in_sizes, int n_in,
                              void* d_out, int out_size, void* d_ws, size_t ws_size,
                              hipStream_t stream)
{
    (void)in_sizes; (void)n_in; (void)out_size; (void)ws_size;
    const float* h     = (const float*)d_in[0];
    const float* x0    = (const float*)d_in[1];
    const float* noise = (const float*)d_in[2];
    const int*   t     = (const int*)d_in[3];
    const int*   row   = (const int*)d_in[4];
    const int*   col   = (const int*)d_in[5];
    const float* W_emb = (const float*)d_in[6];
    const float* b_emb = (const float*)d_in[7];
    const float* eW1   = (const float*)d_in[8];
    const float* eb1   = (const float*)d_in[9];
    const float* eW2   = (const float*)d_in[10];
    const float* eb2   = (const float*)d_in[11];
    const float* cW1   = (const float*)d_in[12];
    const float* cb1   = (const float*)d_in[13];
    const float* cW2   = (const float*)d_in[14];
    const float* nW1   = (const float*)d_in[15];
    const float* nb1   = (const float*)d_in[16];
    const float* nW2   = (const float*)d_in[17];
    const float* nb2   = (const float*)d_in[18];

    // ---- workspace layout
    float* f = (float*)d_ws;
    size_t fo = 0;
    float* temb    = f + fo; fo += NB * TEMBD;
    float* noise_c = f + fo; fo += NNODES * 3;
    float* xt      = f + fo; fo += NNODES * 3;
    float* x_cur   = f + fo; fo += NNODES * 3;
    float* x_agg   = f + fo; fo += NNODES * 3;
    float* m_i     = f + fo; fo += (size_t)NNODES * HID;
    float* msl0    = f + fo; fo += (size_t)NCHUNK * 256;
    float* msl1    = f + fo; fo += (size_t)NCHUNK * 256;
    float* xsl0    = f + fo; fo += (size_t)NCHUNK * 3;
    float* xsl1    = f + fo; fo += (size_t)NCHUNK * 3;

    int* iw = (int*)(f + fo);
    size_t io = 0;
    int* deg    = iw + io; io += NNODES;
    int* cursor = iw + io; io += NNODES;
    int* flag   = iw + io; io += NNODES;
    int* prow   = iw + io; io += NE;
    int* pcol   = iw + io; io += NE;
    int* tag0   = iw + io; io += NCHUNK;
    int* tag1   = iw + io; io += NCHUNK;

    size_t sbase_bytes = ((((char*)(iw + io)) - (char*)d_ws) + 15) & ~(size_t)15;
    short* sb = (short*)((char*)d_ws + sbase_bytes);
    short* wb  = sb;
    size_t so = W_TOTAL;
    short* hh  = sb + so; so += (size_t)NNODES * HID;
    short* hh2 = sb + so; so += (size_t)NNODES * HID;
    short* P12 = sb + so; so += (size_t)NNODES * 512;
    char* wf8 = (char*)(sb + so);   // WF8_TOTAL bytes

    // ---- prologue (14 launches total)
    prep_kernel<<<NB, 256, 0, stream>>>(x0, noise, t, noise_c, xt, temb, deg, (float*)d_out, x_cur);
    csr_hist<<<NE / 256, 256, 0, stream>>>(row, deg);
    csr_scan<<<1, 256, 0, stream>>>(deg, cursor, flag);
    csr_scatter<<<NE / 256, 256, 0, stream>>>(row, col, cursor, prow, pcol);
    convert_weights<<<(W_TOTAL + WF8_TOTAL + 255) / 256, 256, 0, stream>>>(
        W_emb, eW1, eW2, cW1, nW1, nW2, wb, wf8);
    emb_p12_fused<<<NNODES / 16, 1024, 0, stream>>>(
        h, temb, wb + WOFF_EMB, b_emb, wb + WOFF_L(0) + WOFF_AB, eb1, hh, P12);

    short* hc = hh;
    short* hn = hh2;
    for (int l = 0; l < NL; l++) {
        const short* wl = wb + WOFF_L(l);
        const char* wf8l = wf8 + (size_t)l * 131072;
        int last = (l == NL - 1);
        egnn_edge_mfma<<<NE / 64, 256, 0, stream>>>(
            P12, x_cur, prow, pcol,
            eW1 + (size_t)l * 513 * 256 + 512 * 256,
            wf8l, eb2 + (size_t)l * HID,
            wf8l + 65536, cb1 + (size_t)l * HID,
            cW2 + (size_t)l * HID,
            m_i, x_agg, msl0, msl1, xsl0, xsl1, tag0, tag1, last ? 0 : 1);
        if (!last) {
            node_p12_fused<<<NNODES / 16, 1024, 0, stream>>>(
                hc, m_i, cursor, flag, tag0, tag1, msl0, msl1,
                xsl0, xsl1, x_agg, x_cur,
                wl + WOFF_N1, nb1 + (size_t)l * HID,
                wl + WOFF_N2, nb2 + (size_t)l * HID,
                wb + WOFF_L(l + 1) + WOFF_AB, eb1 + (size_t)(l + 1) * HID,
                hn, P12);
            short* tmp = hc; hc = hn; hn = tmp;
        }
    }

    loss_part<<<NB, 256, 0, stream>>>(
        x_cur, xt, noise_c, cursor, flag, tag0, tag1, xsl0, xsl1, x_agg, (float*)d_out);
}